// Round 4
// baseline (331.616 us; speedup 1.0000x reference)
//
#include <hip/hip_runtime.h>
#include <math.h>

#define NU_F 0.0031830988618379067f
#define KTANH 2.885390082f   // 2*log2(e)

typedef _Float16 f16x8  __attribute__((ext_vector_type(8)));
typedef float    f32x4  __attribute__((ext_vector_type(4)));
typedef float    f32x16 __attribute__((ext_vector_type(16)));

// tanh from PRE-SCALED argument zs = 2*log2(e)*z:
// tanh(z) = 1 - 2/(exp2(zs)+1); 4 VALU (2 transcendental)
__device__ __forceinline__ float tanh_pre(float zs) {
    float e = __builtin_amdgcn_exp2f(zs);
    float r = __builtin_amdgcn_rcpf(e + 1.0f);
    return fmaf(-2.0f, r, 1.0f);
}

// pack two f32 -> f16x2 in one u32 (v_cvt_pkrtz_f32_f16), low16 = a
__device__ __forceinline__ unsigned pkf16(float a, float b) {
    auto v = __builtin_amdgcn_cvt_pkrtz(a, b);   // __fp16 ext_vector(2)
    return __builtin_bit_cast(unsigned, v);
}

// LDS-only barrier: order ds ops without draining vmcnt (keeps prefetched
// global B loads in flight across the layer boundary — T4 counted-vmcnt idea).
__device__ __forceinline__ void lds_barrier() {
    asm volatile("s_waitcnt lgkmcnt(0)" ::: "memory");
    __builtin_amdgcn_s_barrier();
}

// ---------------------------------------------------------------------------
// Prep for 32x32x16 B-fragments (gather-read, COALESCED 16B write).
// frag f = (l*4 + nt)*8 + ks  (l=0..6 layer, nt=0..3 N-tile, ks=0..7 K-step)
// lane: n = lane&31 (col), hi = lane>>5 (k-half)
// B layout (32x32x16): col = lane&31, k = (lane>>5)*8 + jj
// channel pairing: real out-channel ch(nt,n) = (nt>>1)*64 + 2n + (nt&1)
// k-row kk = ks*16 + hi*8 + jj (natural channel-in order)
// ---------------------------------------------------------------------------
__global__ void prep_wfrag(const float* __restrict__ Whid, _Float16* __restrict__ wcf)
{
    const int t    = blockIdx.x * 256 + threadIdx.x;   // 0 .. 14335
    const int lane = t & 63;
    const int f    = t >> 6;          // 0..223
    const int ks = f & 7;
    const int nt = (f >> 3) & 3;
    const int l  = f >> 5;
    const int n  = lane & 31;
    const int hi = lane >> 5;
    const int ch = ((nt >> 1) << 6) + n * 2 + (nt & 1);
    const int kk = ks * 16 + hi * 8;
    const float* src = Whid + l * 16384 + kk * 128 + ch;
    f16x8 v;
    #pragma unroll
    for (int jj = 0; jj < 8; ++jj)
        v[jj] = (_Float16)src[jj * 128];
    *(f16x8*)(wcf + (size_t)t * 8) = v;
}

#define RS 68   // H row stride in dwords (16B-aligned rows, bank-spread)
#define MFMA32(A, B, C) __builtin_amdgcn_mfma_f32_32x32x16_f16((A), (B), (C), 0, 0, 0)

// ---------------------------------------------------------------------------
// Fused kernel, 256 thr = 4 waves, 32x32x16 MFMA, B SOFTWARE-PIPELINED.
// H LDS layout: [row][ch], row-major, RS=68 dwords/row, DOUBLE-buffered.
//   deriv blocks: row = point*4 + state (16 pts x 4 jet states = 64 rows)
//   value blocks: row = point (64 pts)
// Tiling: M = 64 rows -> 2 M-tiles of 32; N = 128 ch -> 4 N-tiles of 32.
// Wave wv: mt = wv&1, ntp = wv>>1 -> tiles (mt, ntp*2) and (mt, ntp*2+1).
// D-fragment: col = lane&31, row = (reg&3) + 8*(reg>>2) + 4*(lane>>5)
//   -> with row = p*4+s, reg&3 = STATE: thread holds 4 complete jets.
// Pipeline: B(l) lives in 16 f16x8 regs; after the K-loop consumes them,
// B(l+1) loads issue (dead-value reuse, ~64 VGPR) and complete under the
// epilogue + lds_barrier (no vmcnt drain) + next layer's A ds_reads.
// ---------------------------------------------------------------------------
__global__ __launch_bounds__(256, 4)
void pinn_fused(const float* __restrict__ xf,
                const float* __restrict__ x0,  const float* __restrict__ xbl,
                const float* __restrict__ xbr,
                const float* __restrict__ Win,  const float* __restrict__ bin,
                const float* __restrict__ bhid,
                const float* __restrict__ Wout, const float* __restrict__ bout,
                const _Float16* __restrict__ wcf,
                float* __restrict__ out)
{
    __shared__ unsigned Hh[2][64 * RS];
    __shared__ float xpt[128];
    __shared__ float pbuf[256];
    __shared__ float dots[64];

    const int tid  = threadIdx.x;
    const int lane = tid & 63;
    const int wv   = tid >> 6;
    const int nl   = lane & 31;
    const int hi   = lane >> 5;
    const int mt   = wv & 1;           // M-tile
    const int ntp  = wv >> 1;          // N-tile pair
    const int cdw  = ntp * 32 + nl;    // H dword column (channel pair)
    const int blk  = blockIdx.x;
    const bool isv = (blk >= 8192);

    if (!isv) {
        if (tid < 32) xpt[tid] = xf[blk * 32 + tid];
    } else {
        if (tid < 128) {
            const int vb = blk - 8192;
            const float* src = (vb < 64) ? (x0 + vb * 128)
                             : (vb < 96) ? (xbl + (vb - 64) * 128)
                                         : (xbr + (vb - 96) * 128);
            xpt[tid] = src[tid];
        }
    }

    // ---- prologue prefetch: layer-0 B fragments + bias (hide under input) --
    const _Float16* pb = wcf + ntp * 8192 + lane * 8;
    const float* bptr = bhid + ntp * 64 + nl * 2;
    f16x8 B0[8], B1[8];
    #pragma unroll
    for (int ks = 0; ks < 8; ++ks) {
        B0[ks] = *(const f16x8*)(pb + ks * 512);
        B1[ks] = *(const f16x8*)(pb + 4096 + ks * 512);
    }
    float2 btc = *(const float2*)bptr;

    __syncthreads();   // xpt ready

    // ---- input layer: thread owns channel pair cp -> H buffer 0 ----
    const int cp = tid & 63;
    {
        const float2 w01 = *(const float2*)&Win[cp * 2];
        const float2 w11 = *(const float2*)&Win[128 + cp * 2];
        const float2 bb  = *(const float2*)&bin[cp * 2];
        const float w01sx = w01.x * KTANH, w01sy = w01.y * KTANH;
        const float w11sx = w11.x * KTANH, w11sy = w11.y * KTANH;
        const float bbsx  = bb.x  * KTANH, bbsy  = bb.y  * KTANH;
        if (!isv) {
            const int p0 = wv * 4;
            #pragma unroll
            for (int i = 0; i < 4; ++i) {
                const int p = p0 + i;
                const float x = xpt[2 * p], tt = xpt[2 * p + 1];
                const float ya = tanh_pre(fmaf(x, w01sx, fmaf(tt, w11sx, bbsx)));
                const float yb = tanh_pre(fmaf(x, w01sy, fmaf(tt, w11sy, bbsy)));
                const float da = 1.f - ya * ya, db = 1.f - yb * yb;
                Hh[0][(p * 4 + 0) * RS + cp] = pkf16(ya, yb);
                Hh[0][(p * 4 + 1) * RS + cp] = pkf16(da * w01.x, db * w01.y);
                Hh[0][(p * 4 + 2) * RS + cp] = pkf16(da * w11.x, db * w11.y);
                Hh[0][(p * 4 + 3) * RS + cp] =
                    pkf16(-2.f * ya * da * w01.x * w01.x,
                          -2.f * yb * db * w01.y * w01.y);
            }
        } else {
            const int p0 = wv * 16;
            #pragma unroll
            for (int i = 0; i < 16; ++i) {
                const int p = p0 + i;
                const float x = xpt[2 * p], tt = xpt[2 * p + 1];
                const float ya = tanh_pre(fmaf(x, w01sx, fmaf(tt, w11sx, bbsx)));
                const float yb = tanh_pre(fmaf(x, w01sy, fmaf(tt, w11sy, bbsy)));
                Hh[0][p * RS + cp] = pkf16(ya, yb);
            }
        }
    }
    lds_barrier();

    // A-read base: row = mt*32 + nl, k-offset hi*8 f16 = hi*4 dwords
    const int arow = (mt * 32 + nl) * RS + hi * 4;

    if (!isv) {
        // ================= derivative path =================
        for (int l = 0; l < 7; ++l) {
            const unsigned* Hc = Hh[l & 1];
            unsigned*       Hn = Hh[(l & 1) ^ 1];
            const float bbs0 = btc.x * KTANH, bbs1 = btc.y * KTANH;

            f32x16 a0, a1;
            #pragma unroll
            for (int i = 0; i < 16; ++i) { a0[i] = 0.f; a1[i] = 0.f; }

            #pragma unroll
            for (int ks = 0; ks < 8; ++ks) {
                const f16x8 A = *(const f16x8*)&Hc[arow + ks * 8];
                a0 = MFMA32(A, B0[ks], a0);
                a1 = MFMA32(A, B1[ks], a1);
            }

            // prefetch next layer's B + bias (old B dead -> reg reuse)
            pb += 16384;
            if (l < 6) {
                #pragma unroll
                for (int ks = 0; ks < 8; ++ks) {
                    B0[ks] = *(const f16x8*)(pb + ks * 512);
                    B1[ks] = *(const f16x8*)(pb + 4096 + ks * 512);
                }
                btc = *(const float2*)(bptr + 128);
                bptr += 128;
            }

            // in-thread jet epilogue: reg q*4+s = (point mt*8+2q+hi, state s)
            #pragma unroll
            for (int q = 0; q < 4; ++q) {
                float h0[4], h1[4];
                {
                    const float zx = a0[q * 4 + 1], zt = a0[q * 4 + 2],
                                zxx = a0[q * 4 + 3];
                    const float y = tanh_pre(fmaf(a0[q * 4 + 0], KTANH, bbs0));
                    const float d = fmaf(-y, y, 1.f);
                    const float m = d * zx;
                    h0[0] = y; h0[1] = m; h0[2] = d * zt;
                    h0[3] = fmaf(d, zxx, -2.f * (y * m) * zx);
                }
                {
                    const float zx = a1[q * 4 + 1], zt = a1[q * 4 + 2],
                                zxx = a1[q * 4 + 3];
                    const float y = tanh_pre(fmaf(a1[q * 4 + 0], KTANH, bbs1));
                    const float d = fmaf(-y, y, 1.f);
                    const float m = d * zx;
                    h1[0] = y; h1[1] = m; h1[2] = d * zt;
                    h1[3] = fmaf(d, zxx, -2.f * (y * m) * zx);
                }
                const int rbase = mt * 32 + q * 8 + hi * 4;
                #pragma unroll
                for (int s = 0; s < 4; ++s)
                    Hn[(rbase + s) * RS + cdw] = pkf16(h0[s], h1[s]);
            }
            lds_barrier();   // Hn complete before it becomes Hc
        }
    } else {
        // ================= value-only path =================
        for (int l = 0; l < 7; ++l) {
            const unsigned* Hc = Hh[l & 1];
            unsigned*       Hn = Hh[(l & 1) ^ 1];
            const float bbs0 = btc.x * KTANH, bbs1 = btc.y * KTANH;

            f32x16 a0, a1;
            #pragma unroll
            for (int i = 0; i < 16; ++i) { a0[i] = 0.f; a1[i] = 0.f; }

            #pragma unroll
            for (int ks = 0; ks < 8; ++ks) {
                const f16x8 A = *(const f16x8*)&Hc[arow + ks * 8];
                a0 = MFMA32(A, B0[ks], a0);
                a1 = MFMA32(A, B1[ks], a1);
            }

            pb += 16384;
            if (l < 6) {
                #pragma unroll
                for (int ks = 0; ks < 8; ++ks) {
                    B0[ks] = *(const f16x8*)(pb + ks * 512);
                    B1[ks] = *(const f16x8*)(pb + 4096 + ks * 512);
                }
                btc = *(const float2*)(bptr + 128);
                bptr += 128;
            }

            #pragma unroll
            for (int r = 0; r < 16; ++r) {
                const float y0 = tanh_pre(fmaf(a0[r], KTANH, bbs0));
                const float y1 = tanh_pre(fmaf(a1[r], KTANH, bbs1));
                const int row = mt * 32 + (r & 3) + (r >> 2) * 8 + hi * 4;
                Hn[row * RS + cdw] = pkf16(y0, y1);
            }
            lds_barrier();
        }
    }

    // ---- output layer: read H buffer 1 (after 7 layers) ----
    {
        const int st = lane;           // H row 0..63
        const int cb = wv * 16;        // 16 dwords = 32 channels per chunk
        float part = 0.f;
        #pragma unroll
        for (int c8 = 0; c8 < 4; ++c8) {
            const f16x8 hv = *(const f16x8*)&Hh[1][st * RS + cb + c8 * 4];
            const float4 w1 = *(const float4*)&Wout[wv * 32 + c8 * 8];
            const float4 w2 = *(const float4*)&Wout[wv * 32 + c8 * 8 + 4];
            part = fmaf((float)hv[0], w1.x, part);
            part = fmaf((float)hv[1], w1.y, part);
            part = fmaf((float)hv[2], w1.z, part);
            part = fmaf((float)hv[3], w1.w, part);
            part = fmaf((float)hv[4], w2.x, part);
            part = fmaf((float)hv[5], w2.y, part);
            part = fmaf((float)hv[6], w2.z, part);
            part = fmaf((float)hv[7], w2.w, part);
        }
        pbuf[wv * 64 + st] = part;
    }
    lds_barrier();
    if (tid < 64) {
        const float sum = (pbuf[tid] + pbuf[64 + tid])
                        + (pbuf[128 + tid] + pbuf[192 + tid]);
        // deriv rows are p*4+s -> dot index s*16+p; value rows are p -> p
        const int d = isv ? tid : ((tid & 3) * 16 + (tid >> 2));
        dots[d] = sum;
    }
    lds_barrier();
    if (!isv) {
        if (tid < 16) {
            const float u = dots[tid] + bout[0];
            out[8192 + blk * 16 + tid] =
                dots[32 + tid] + u * dots[16 + tid] - NU_F * dots[48 + tid];
        }
    } else {
        if (tid < 64) out[(blk - 8192) * 64 + tid] = dots[tid] + bout[0];
    }
}

extern "C" void kernel_launch(void* const* d_in, const int* in_sizes, int n_in,
                              void* d_out, int out_size, void* d_ws, size_t ws_size,
                              hipStream_t stream) {
    (void)in_sizes; (void)n_in; (void)ws_size; (void)out_size;
    const float* xf   = (const float*)d_in[0];
    const float* x0   = (const float*)d_in[1];
    const float* xbl  = (const float*)d_in[2];
    const float* xbr  = (const float*)d_in[3];
    const float* Win  = (const float*)d_in[4];
    const float* bin  = (const float*)d_in[5];
    const float* Whid = (const float*)d_in[6];
    const float* bhid = (const float*)d_in[7];
    const float* Wout = (const float*)d_in[8];
    const float* bout = (const float*)d_in[9];
    float* out = (float*)d_out;

    _Float16* wcf = (_Float16*)d_ws;   // 7*4*8 fragments * 1 KiB = 224 KiB

    hipLaunchKernelGGL(prep_wfrag, dim3(14336 / 256), dim3(256), 0, stream,
                       Whid, wcf);
    hipLaunchKernelGGL(pinn_fused, dim3(8192 + 128), dim3(256), 0, stream,
                       xf, x0, xbl, xbr, Win, bin, bhid, Wout, bout, wcf, out);
}

// Round 6
// 214.897 us; speedup vs baseline: 1.5431x; 1.5431x over previous
//
#include <hip/hip_runtime.h>
#include <math.h>

#define NU_F 0.0031830988618379067f
#define KTANH 2.885390082f   // 2*log2(e)

typedef _Float16 f16x8 __attribute__((ext_vector_type(8)));
typedef float    f32x4 __attribute__((ext_vector_type(4)));

// tanh from PRE-SCALED argument zs = 2*log2(e)*z:
// tanh(z) = 1 - 2/(exp2(zs)+1); 4 VALU (2 transcendental)
__device__ __forceinline__ float tanh_pre(float zs) {
    float e = __builtin_amdgcn_exp2f(zs);
    float r = __builtin_amdgcn_rcpf(e + 1.0f);
    return fmaf(-2.0f, r, 1.0f);
}

// pack two f32 -> f16x2 in one u32 (v_cvt_pkrtz_f32_f16), low16 = a
__device__ __forceinline__ unsigned pkf16(float a, float b) {
    auto v = __builtin_amdgcn_cvt_pkrtz(a, b);   // __fp16 ext_vector(2)
    return __builtin_bit_cast(unsigned, v);
}

// LDS-only barrier: order LDS ops across waves WITHOUT draining vmcnt,
// so prefetched global B loads stay in flight across layer boundaries.
// Used ONLY where the producing ops are LDS writes (layer epilogues).
__device__ __forceinline__ void lds_barrier() {
    asm volatile("s_waitcnt lgkmcnt(0)" ::: "memory");
    __builtin_amdgcn_s_barrier();
}

// ---------------------------------------------------------------------------
// Prep (gather-read, COALESCED-write): thread t owns dst dwords t*8..+7.
//   dst = fid*512 + lane*8 + jj ; fid = (l*8+nt)*4+ks ; lane = q*16+nn
//   k = ks*32 + q*8 + jj
// channel-PAIR map (4 waves x 2 tiles): c = (nt>>1)*32 + nn*2 + (nt&1)
// (wave wv owns tiles 2wv,2wv+1 -> channels wv*32 + nn*2 + j)
// ---------------------------------------------------------------------------
__global__ void prep_wfrag(const float* __restrict__ Whid, _Float16* __restrict__ wcf)
{
    const int t    = blockIdx.x * 256 + threadIdx.x;   // 0 .. 14335
    const int lane = t & 63;
    const int fid  = t >> 6;          // (l*8 + nt)*4 + ks, 0..223
    const int ks = fid & 3;
    const int nt = (fid >> 2) & 7;
    const int l  = fid >> 5;
    const int q  = lane >> 4;
    const int nn = lane & 15;
    const int c  = ((nt >> 1) << 5) + nn * 2 + (nt & 1);
    const int k0 = ks * 32 + q * 8;
    const float* src = Whid + l * 16384 + k0 * 128 + c;
    f16x8 v;
    #pragma unroll
    for (int jj = 0; jj < 8; ++jj)
        v[jj] = (_Float16)src[jj * 128];
    *(f16x8*)(wcf + (size_t)t * 8) = v;
}

#define HR 68
#define MFMA(A, B, C) __builtin_amdgcn_mfma_f32_16x16x32_f16((A), (B), (C), 0, 0, 0)

// ---------------------------------------------------------------------------
// Fused kernel, 256 thr = 4 waves; wave wv owns N-tiles 2wv,2wv+1
// (channels wv*32 + nn*2 + {0,1}).  r2 structure (1x B L2-traffic) plus:
//  - H DOUBLE-buffered (2 x 64 x 68 dwords) -> ONE barrier per layer
//  - lds_barrier (no vmcnt drain) -> loads survive layer boundaries
//  - depth-1 B prefetch: next layer's ks=0 fragment pair + bias (18 VGPR)
//    issued after the K-loop, completes under the jet epilogue.
// Round-4 lesson: full 16-fragment prefetch (64 VGPR) spilled -> 476 MB
// scratch writes. Depth-1 keeps the register budget ~80 < 128 cap.
// ---------------------------------------------------------------------------
__global__ __launch_bounds__(256, 4)
void pinn_fused(const float* __restrict__ xf,
                const float* __restrict__ x0,  const float* __restrict__ xbl,
                const float* __restrict__ xbr,
                const float* __restrict__ Win,  const float* __restrict__ bin,
                const float* __restrict__ bhid,
                const float* __restrict__ Wout, const float* __restrict__ bout,
                const _Float16* __restrict__ wcf,
                float* __restrict__ out)
{
    __shared__ unsigned Hh[2][64 * HR];
    __shared__ float xpt[128];
    __shared__ float pbuf[256];
    __shared__ float dots[64];

    const int tid  = threadIdx.x;
    const int lane = tid & 63;
    const int wv   = tid >> 6;         // wave 0..3 -> N-tiles 2wv,2wv+1
    const int lm   = lane & 15;
    const int lq   = lane >> 4;
    const int blk  = blockIdx.x;
    const bool isv = (blk >= 8192);

    if (!isv) {
        if (tid < 32) xpt[tid] = xf[blk * 32 + tid];
    } else {
        if (tid < 128) {
            const int vb = blk - 8192;
            const float* src = (vb < 64) ? (x0 + vb * 128)
                             : (vb < 96) ? (xbl + (vb - 64) * 128)
                                         : (xbr + (vb - 96) * 128);
            xpt[tid] = src[tid];
        }
    }

    // ---- prologue prefetch: layer-0 ks=0 B pair + bias (18 VGPR) ----
    const _Float16* pb0 = wcf + (wv * 2 + 0) * 2048 + lane * 8;
    const _Float16* pb1 = wcf + (wv * 2 + 1) * 2048 + lane * 8;
    const float* bptr = bhid + wv * 32 + lm * 2;
    f16x8 cB0 = *(const f16x8*)pb0;
    f16x8 cB1 = *(const f16x8*)pb1;
    float2 btc = *(const float2*)bptr;

    __syncthreads();   // xpt ready (full barrier: global->LDS staging above)

    // ---- input layer: thread owns channel pair cp -> H buffer 0 ----
    const int cp = tid & 63;
    {
        const float2 w01 = *(const float2*)&Win[cp * 2];
        const float2 w11 = *(const float2*)&Win[128 + cp * 2];
        const float2 bb  = *(const float2*)&bin[cp * 2];
        const float w01sx = w01.x * KTANH, w01sy = w01.y * KTANH;
        const float w11sx = w11.x * KTANH, w11sy = w11.y * KTANH;
        const float bbsx  = bb.x  * KTANH, bbsy  = bb.y  * KTANH;
        if (!isv) {
            const int p0 = wv * 4;
            #pragma unroll
            for (int i = 0; i < 4; ++i) {
                const int p = p0 + i;
                const float x = xpt[2 * p], tt = xpt[2 * p + 1];
                const float ya = tanh_pre(fmaf(x, w01sx, fmaf(tt, w11sx, bbsx)));
                const float yb = tanh_pre(fmaf(x, w01sy, fmaf(tt, w11sy, bbsy)));
                const float da = 1.f - ya * ya, db = 1.f - yb * yb;
                Hh[0][(0 * 16 + p) * HR + cp] = pkf16(ya, yb);
                Hh[0][(1 * 16 + p) * HR + cp] = pkf16(da * w01.x, db * w01.y);
                Hh[0][(2 * 16 + p) * HR + cp] = pkf16(da * w11.x, db * w11.y);
                Hh[0][(3 * 16 + p) * HR + cp] =
                    pkf16(-2.f * ya * da * w01.x * w01.x,
                          -2.f * yb * db * w01.y * w01.y);
            }
        } else {
            const int p0 = wv * 16;
            #pragma unroll
            for (int i = 0; i < 16; ++i) {
                const int p = p0 + i;
                const float x = xpt[2 * p], tt = xpt[2 * p + 1];
                const float ya = tanh_pre(fmaf(x, w01sx, fmaf(tt, w11sx, bbsx)));
                const float yb = tanh_pre(fmaf(x, w01sy, fmaf(tt, w11sy, bbsy)));
                Hh[0][p * HR + cp] = pkf16(ya, yb);
            }
        }
    }
    lds_barrier();

    const int wc = wv * 16 + lm;   // epilogue dword column (channel pair)

    if (!isv) {
        // ================= derivative path =================
        for (int l = 0; l < 7; ++l) {
            const unsigned* Hc = Hh[l & 1];
            unsigned*       Hn = Hh[(l & 1) ^ 1];
            const float bbs0 = btc.x * KTANH, bbs1 = btc.y * KTANH;

            f32x4 acc[4][2];   // [state][tile j]
            #pragma unroll
            for (int s = 0; s < 4; ++s)
                #pragma unroll
                for (int j = 0; j < 2; ++j) acc[s][j] = (f32x4){0.f, 0.f, 0.f, 0.f};

            {   // ks = 0: B pair from the cross-barrier prefetch registers
                const int ro = lq * 4;
                const f16x8 ah0 = *(const f16x8*)&Hc[(0 * 16 + lm) * HR + ro];
                const f16x8 ah1 = *(const f16x8*)&Hc[(1 * 16 + lm) * HR + ro];
                const f16x8 ah2 = *(const f16x8*)&Hc[(2 * 16 + lm) * HR + ro];
                const f16x8 ah3 = *(const f16x8*)&Hc[(3 * 16 + lm) * HR + ro];
                acc[0][0] = MFMA(ah0, cB0, acc[0][0]);
                acc[1][0] = MFMA(ah1, cB0, acc[1][0]);
                acc[2][0] = MFMA(ah2, cB0, acc[2][0]);
                acc[3][0] = MFMA(ah3, cB0, acc[3][0]);
                acc[0][1] = MFMA(ah0, cB1, acc[0][1]);
                acc[1][1] = MFMA(ah1, cB1, acc[1][1]);
                acc[2][1] = MFMA(ah2, cB1, acc[2][1]);
                acc[3][1] = MFMA(ah3, cB1, acc[3][1]);
            }
            #pragma unroll
            for (int ks = 1; ks < 4; ++ks) {
                const int ro = ks * 16 + lq * 4;
                const f16x8 ah0 = *(const f16x8*)&Hc[(0 * 16 + lm) * HR + ro];
                const f16x8 ah1 = *(const f16x8*)&Hc[(1 * 16 + lm) * HR + ro];
                const f16x8 ah2 = *(const f16x8*)&Hc[(2 * 16 + lm) * HR + ro];
                const f16x8 ah3 = *(const f16x8*)&Hc[(3 * 16 + lm) * HR + ro];
                const f16x8 b0 = *(const f16x8*)(pb0 + ks * 512);
                const f16x8 b1 = *(const f16x8*)(pb1 + ks * 512);
                acc[0][0] = MFMA(ah0, b0, acc[0][0]);
                acc[1][0] = MFMA(ah1, b0, acc[1][0]);
                acc[2][0] = MFMA(ah2, b0, acc[2][0]);
                acc[3][0] = MFMA(ah3, b0, acc[3][0]);
                acc[0][1] = MFMA(ah0, b1, acc[0][1]);
                acc[1][1] = MFMA(ah1, b1, acc[1][1]);
                acc[2][1] = MFMA(ah2, b1, acc[2][1]);
                acc[3][1] = MFMA(ah3, b1, acc[3][1]);
            }

            // depth-1 prefetch: next layer's ks=0 pair + bias (hides under
            // the epilogue; survives lds_barrier since no vmcnt drain)
            pb0 += 16384; pb1 += 16384;
            if (l < 6) {
                cB0 = *(const f16x8*)pb0;
                cB1 = *(const f16x8*)pb1;
                btc = *(const float2*)(bptr + 128);
                bptr += 128;
            }

            #pragma unroll
            for (int r = 0; r < 4; ++r) {
                const int p = lq * 4 + r;
                float h[2][4];   // [tile j][state]
                #pragma unroll
                for (int j = 0; j < 2; ++j) {
                    const float zx  = acc[1][j][r];
                    const float zt  = acc[2][j][r];
                    const float zxx = acc[3][j][r];
                    const float y = tanh_pre(fmaf(acc[0][j][r], KTANH,
                                                  j ? bbs1 : bbs0));
                    const float d = fmaf(-y, y, 1.f);
                    const float m = d * zx;
                    h[j][0] = y;
                    h[j][1] = m;
                    h[j][2] = d * zt;
                    h[j][3] = fmaf(d, zxx, -2.f * (y * m) * zx);
                }
                #pragma unroll
                for (int s = 0; s < 4; ++s)
                    Hn[(s * 16 + p) * HR + wc] = pkf16(h[0][s], h[1][s]);
            }
            lds_barrier();   // Hn complete before it becomes Hc
        }
    } else {
        // ================= value-only path =================
        for (int l = 0; l < 7; ++l) {
            const unsigned* Hc = Hh[l & 1];
            unsigned*       Hn = Hh[(l & 1) ^ 1];
            const float bbs0 = btc.x * KTANH, bbs1 = btc.y * KTANH;

            f32x4 acc[4][2];   // [m-tile][tile j]
            #pragma unroll
            for (int mt = 0; mt < 4; ++mt)
                #pragma unroll
                for (int j = 0; j < 2; ++j) acc[mt][j] = (f32x4){0.f, 0.f, 0.f, 0.f};

            {   // ks = 0 with prefetched pair
                const int ro = lq * 4;
                f16x8 ah[4];
                #pragma unroll
                for (int mt = 0; mt < 4; ++mt)
                    ah[mt] = *(const f16x8*)&Hc[(mt * 16 + lm) * HR + ro];
                #pragma unroll
                for (int mt = 0; mt < 4; ++mt) {
                    acc[mt][0] = MFMA(ah[mt], cB0, acc[mt][0]);
                    acc[mt][1] = MFMA(ah[mt], cB1, acc[mt][1]);
                }
            }
            #pragma unroll
            for (int ks = 1; ks < 4; ++ks) {
                const int ro = ks * 16 + lq * 4;
                f16x8 ah[4];
                #pragma unroll
                for (int mt = 0; mt < 4; ++mt)
                    ah[mt] = *(const f16x8*)&Hc[(mt * 16 + lm) * HR + ro];
                const f16x8 b0 = *(const f16x8*)(pb0 + ks * 512);
                const f16x8 b1 = *(const f16x8*)(pb1 + ks * 512);
                #pragma unroll
                for (int mt = 0; mt < 4; ++mt) {
                    acc[mt][0] = MFMA(ah[mt], b0, acc[mt][0]);
                    acc[mt][1] = MFMA(ah[mt], b1, acc[mt][1]);
                }
            }

            pb0 += 16384; pb1 += 16384;
            if (l < 6) {
                cB0 = *(const f16x8*)pb0;
                cB1 = *(const f16x8*)pb1;
                btc = *(const float2*)(bptr + 128);
                bptr += 128;
            }

            #pragma unroll
            for (int mt = 0; mt < 4; ++mt) {
                #pragma unroll
                for (int r = 0; r < 4; ++r) {
                    const int p = mt * 16 + lq * 4 + r;
                    const float y0 = tanh_pre(fmaf(acc[mt][0][r], KTANH, bbs0));
                    const float y1 = tanh_pre(fmaf(acc[mt][1][r], KTANH, bbs1));
                    Hn[p * HR + wc] = pkf16(y0, y1);
                }
            }
            lds_barrier();
        }
    }

    // ---- output layer: read H buffer 1 (after 7 layers: 0->1->...->1) ----
    {
        const int st = lane;           // H row 0..63
        const int cb = wv * 16;        // 16 dwords = 32 channels per chunk
        float part = 0.f;
        #pragma unroll
        for (int c8 = 0; c8 < 4; ++c8) {
            const f16x8 hv = *(const f16x8*)&Hh[1][st * HR + cb + c8 * 4];
            const float4 w1 = *(const float4*)&Wout[wv * 32 + c8 * 8];
            const float4 w2 = *(const float4*)&Wout[wv * 32 + c8 * 8 + 4];
            part = fmaf((float)hv[0], w1.x, part);
            part = fmaf((float)hv[1], w1.y, part);
            part = fmaf((float)hv[2], w1.z, part);
            part = fmaf((float)hv[3], w1.w, part);
            part = fmaf((float)hv[4], w2.x, part);
            part = fmaf((float)hv[5], w2.y, part);
            part = fmaf((float)hv[6], w2.z, part);
            part = fmaf((float)hv[7], w2.w, part);
        }
        pbuf[wv * 64 + st] = part;
    }
    lds_barrier();
    if (tid < 64)
        dots[tid] = (pbuf[tid] + pbuf[64 + tid]) + (pbuf[128 + tid] + pbuf[192 + tid]);
    lds_barrier();
    if (!isv) {
        if (tid < 16) {
            const float u = dots[tid] + bout[0];
            out[8192 + blk * 16 + tid] =
                dots[32 + tid] + u * dots[16 + tid] - NU_F * dots[48 + tid];
        }
    } else {
        if (tid < 64) out[(blk - 8192) * 64 + tid] = dots[tid] + bout[0];
    }
}

extern "C" void kernel_launch(void* const* d_in, const int* in_sizes, int n_in,
                              void* d_out, int out_size, void* d_ws, size_t ws_size,
                              hipStream_t stream) {
    (void)in_sizes; (void)n_in; (void)ws_size; (void)out_size;
    const float* xf   = (const float*)d_in[0];
    const float* x0   = (const float*)d_in[1];
    const float* xbl  = (const float*)d_in[2];
    const float* xbr  = (const float*)d_in[3];
    const float* Win  = (const float*)d_in[4];
    const float* bin  = (const float*)d_in[5];
    const float* Whid = (const float*)d_in[6];
    const float* bhid = (const float*)d_in[7];
    const float* Wout = (const float*)d_in[8];
    const float* bout = (const float*)d_in[9];
    float* out = (float*)d_out;

    _Float16* wcf = (_Float16*)d_ws;   // 7*128*128 f16 = 224 KiB

    hipLaunchKernelGGL(prep_wfrag, dim3(14336 / 256), dim3(256), 0, stream,
                       Whid, wcf);
    hipLaunchKernelGGL(pinn_fused, dim3(8192 + 128), dim3(256), 0, stream,
                       xf, x0, xbl, xbr, Win, bin, bhid, Wout, bout, wcf, out);
}